// Round 8
// baseline (783.286 us; speedup 1.0000x reference)
//
#include <hip/hip_runtime.h>

#define NN 100000
#define NP 100096          // 782 * 128, padded row count
#define EE 300000
#define DIN 128
#define HD  256
#define HD2 512
#define NL  4
#define NG  512
#define BN_EPS 1e-5f

typedef __attribute__((ext_vector_type(8))) short s8v;      // bf16x8 frag (4 VGPRs)
typedef __attribute__((ext_vector_type(4))) float f4v;      // fp32x4 acc

typedef unsigned short ushort_t;

// float -> bf16, round-to-nearest-even
static __device__ inline ushort_t f2bf(float f) {
    unsigned u = __float_as_uint(f);
    unsigned r = (u + 0x7fffu + ((u >> 16) & 1u)) >> 16;
    return (ushort_t)r;
}
static __device__ inline float bf2f(ushort_t h) {
    return __uint_as_float(((unsigned)h) << 16);
}
// bf16 pair unpack from packed u32: low half needs shift, high half mask-only
static __device__ inline float blo(unsigned v) { return __uint_as_float(v << 16); }
static __device__ inline float bhi(unsigned v) { return __uint_as_float(v & 0xffff0000u); }

// accumulate 8 channels of BN+relu'd row segment: A[i] += wg * relu(z*sc+sh)
static __device__ inline void gacc(float* A, const uint4 u,
                                   const float4 s0, const float4 s1,
                                   const float4 h0, const float4 h1, float wg) {
    A[0] += wg * fmaxf(blo(u.x) * s0.x + h0.x, 0.f);
    A[1] += wg * fmaxf(bhi(u.x) * s0.y + h0.y, 0.f);
    A[2] += wg * fmaxf(blo(u.y) * s0.z + h0.z, 0.f);
    A[3] += wg * fmaxf(bhi(u.y) * s0.w + h0.w, 0.f);
    A[4] += wg * fmaxf(blo(u.z) * s1.x + h1.x, 0.f);
    A[5] += wg * fmaxf(bhi(u.z) * s1.y + h1.y, 0.f);
    A[6] += wg * fmaxf(blo(u.w) * s1.z + h1.z, 0.f);
    A[7] += wg * fmaxf(bhi(u.w) * s1.w + h1.w, 0.f);
}

// async global->LDS, 16B per lane; LDS dest = uniform base + lane*16
#define GLOAD_LDS16(g, l) __builtin_amdgcn_global_load_lds( \
    (const __attribute__((address_space(1))) unsigned int*)(const void*)(g), \
    (__attribute__((address_space(3))) unsigned int*)(void*)(l), 16, 0, 0)

// s_waitcnt immediates: vmcnt[3:0] | expcnt(7)<<4 | lgkmcnt(15)<<8 | vmcnt[5:4]<<14
#define WAITCNT_VM8 0xF78
#define WAITCNT_VM4 0xF74
#define WAITCNT_VM0 0xF70

// ---------------------------------------------------------------------------
// Weight packing into MFMA-fragment order so staging is contiguous 1KB
// bursts. Unit = 1KB = [lane L][e 0..7] bf16. Fragment built directly in an
// ext_vector register (no address-taken stack array).
// W1 input [NL][HD][HD2] f32 (in x out). Unit (l, c, u): kk=u>>1, nt=u&1;
//   value = W1[l][kk*32 + (L>>4)*8 + e][c*32 + nt*16 + (L&15)].
__global__ __launch_bounds__(256) void pack_w1_kernel(
    const float* __restrict__ W1, ushort_t* __restrict__ W1P)
{
    const int t = threadIdx.x, L = t & 63;
    const int gu = blockIdx.x * 4 + (t >> 6);      // 0..1023
    const int l = gu >> 8, rem = gu & 255;
    const int c = rem >> 4, u = rem & 15;
    const int kk = u >> 1, nt = u & 1;
    const int h  = c * 32 + nt * 16 + (L & 15);
    const int k0 = kk * 32 + (L >> 4) * 8;
    const float* src = W1 + (size_t)l * HD * HD2;
    s8v v;
#pragma unroll
    for (int e = 0; e < 8; ++e)
        v[e] = (short)f2bf(src[(size_t)(k0 + e) * HD2 + h]);
    *(s8v*)(W1P + (size_t)gu * 512 + L * 8) = v;
}

// W2 input [NL][HD2][HD] f32. Unit (l, c, nt):
//   value = W2[l][c*32 + (L>>4)*8 + e][nt*16 + (L&15)].
__global__ __launch_bounds__(256) void pack_w2_kernel(
    const float* __restrict__ W2, ushort_t* __restrict__ W2P)
{
    const int t = threadIdx.x, L = t & 63;
    const int gu = blockIdx.x * 4 + (t >> 6);      // 0..1023
    const int l = gu >> 8, rem = gu & 255;
    const int c = rem >> 4, nt = rem & 15;
    const int h  = nt * 16 + (L & 15);
    const int k0 = c * 32 + (L >> 4) * 8;
    const float* src = W2 + (size_t)l * HD2 * HD;
    s8v v;
#pragma unroll
    for (int e = 0; e < 8; ++e)
        v[e] = (short)f2bf(src[(size_t)(k0 + e) * HD + h]);
    *(s8v*)(W2P + (size_t)gu * 512 + L * 8) = v;
}

// W_in input [DIN][HD] f32 (in x out), 64 units (kk=u>>4 in [0,4), nt=u&15):
//   value = Win[kk*32 + (L>>4)*8 + e][nt*16 + (L&15)].
__global__ __launch_bounds__(256) void pack_win_kernel(
    const float* __restrict__ Win, ushort_t* __restrict__ WinP)
{
    const int t = threadIdx.x, L = t & 63;
    const int gu = blockIdx.x * 4 + (t >> 6);      // 0..63
    const int kk = gu >> 4, nt = gu & 15;
    const int h  = nt * 16 + (L & 15);
    const int k0 = kk * 32 + (L >> 4) * 8;
    s8v v;
#pragma unroll
    for (int e = 0; e < 8; ++e)
        v[e] = (short)f2bf(Win[(size_t)(k0 + e) * HD + h]);
    *(s8v*)(WinP + (size_t)gu * 512 + L * 8) = v;
}

// ---------------------------------------------------------------------------
// Input projection: z = relu(x @ W_in + b_in). W_in (64KB packed) is fully
// LDS-resident: stage once, no inner barriers, 64 MFMAs/wave. Reads x in f32
// directly (in-register cvt).
// ---------------------------------------------------------------------------
__global__ __launch_bounds__(512, 2) void inproj_kernel(
    const float* __restrict__ x,        // [NN, DIN] f32
    const ushort_t* __restrict__ WinP,  // [64 units x 512] packed bf16
    const float* __restrict__ bias,     // [HD]
    ushort_t* __restrict__ C)           // [NP, HD] bf16
{
    extern __shared__ char smem[];
    ushort_t* Ws = (ushort_t*)smem;     // 64 KB, epilogue-overlaid as Cs
    const int tid = threadIdx.x;
    const int w   = tid >> 6;
    const int L   = tid & 63;
    const int lm  = L & 15;
    const int q   = L >> 4;
    const int row0 = blockIdx.x * 128;

    // stage all 64 weight units (8 per wave), one contiguous 1KB burst each
#pragma unroll
    for (int i = 0; i < 8; ++i) {
        const int u = w * 8 + i;
        GLOAD_LDS16(WinP + u * 512 + L * 8, Ws + u * 512);
    }

    // A-frags from x (f32 -> bf16 in-register); clamp padded rows
    const int row = row0 + w * 16 + lm;
    const float* xr = x + (size_t)min(row, NN - 1) * DIN;
    s8v a[4];
#pragma unroll
    for (int kk = 0; kk < 4; ++kk) {
        const float4 u0 = *(const float4*)(xr + kk * 32 + q * 8);
        const float4 u1 = *(const float4*)(xr + kk * 32 + q * 8 + 4);
        s8v v;
        v[0] = (short)f2bf(u0.x); v[1] = (short)f2bf(u0.y);
        v[2] = (short)f2bf(u0.z); v[3] = (short)f2bf(u0.w);
        v[4] = (short)f2bf(u1.x); v[5] = (short)f2bf(u1.y);
        v[6] = (short)f2bf(u1.z); v[7] = (short)f2bf(u1.w);
        a[kk] = v;
    }
    __builtin_amdgcn_s_waitcnt(WAITCNT_VM0);
    __syncthreads();

    f4v acc[16] = {};
#pragma unroll
    for (int kk = 0; kk < 4; ++kk) {
#pragma unroll
        for (int nt = 0; nt < 16; ++nt) {
            s8v b = *(const s8v*)&Ws[(kk * 16 + nt) * 512 + L * 8];
            acc[nt] = __builtin_amdgcn_mfma_f32_16x16x32_bf16(a[kk], b, acc[nt], 0, 0, 0);
        }
    }
    __syncthreads();

    // epilogue: bias + relu + bf16 via LDS bounce for coalesced 16B stores
    ushort_t* Cs = Ws;
#pragma unroll
    for (int nt = 0; nt < 16; ++nt) {
        const float bj = bias[nt * 16 + lm];
#pragma unroll
        for (int r = 0; r < 4; ++r) {
            const int rr = w * 16 + q * 4 + r;
            Cs[rr * 256 + nt * 16 + lm] = f2bf(fmaxf(acc[nt][r] + bj, 0.f));
        }
    }
    __syncthreads();
#pragma unroll
    for (int i = 0; i < 8; ++i) {
        const int idx = i * 512 + tid;       // 16B unit among 4096
        const int rr = idx >> 5, ch = idx & 31;
        const s8v v = *(const s8v*)&Cs[idx * 8];
        *(s8v*)(C + (size_t)(row0 + rr) * HD + ch * 8) = v;
    }
}

// ---------------------------------------------------------------------------
// Fused GIN MLP v2 (measured optimum — FROZEN):
// z = (agg @ W1 + b1).relu() @ W2 + b2, plus column stats (into a per-layer
// stats slot).
// ---------------------------------------------------------------------------
__global__ __launch_bounds__(512, 4) void fused_mlp_kernel(
    const ushort_t* __restrict__ A,      // [NP, HD] bf16 (aggregate out)
    const ushort_t* __restrict__ W1l,    // [256 units x 512] packed bf16
    const float*    __restrict__ b1l,    // [HD2]
    const ushort_t* __restrict__ W2l,    // [256 units x 512] packed bf16
    const float*    __restrict__ b2l,    // [HD]
    ushort_t* __restrict__ C,            // [NP, HD] bf16 (pre-BN z)
    float* __restrict__ stats)           // [2*HD] slot: col sum / sumsq
{
    extern __shared__ char smem[];
    ushort_t* lds = (ushort_t*)smem;
    const int tid = threadIdx.x;
    const int w   = tid >> 6;            // wave 0..7 -> rows [w*16, w*16+16)
    const int L   = tid & 63;
    const int lm  = L & 15;
    const int q   = L >> 4;
    const int row0 = blockIdx.x * 128;

    // LDS map (bytes): 0..32767 buf0 | 32768..65535 buf1 |
    // 65536..75775 hchunk (8 x 1280) | 75776..77823 b1s | rest spare.
    // Epilogue overlay: Cs 0..65535 | ssum 65536..73727 | ssq 73728..81919.
    float* b1s = (float*)(smem + 75776);
    char*  hcb = smem + 65536 + w * 1280;   // wave-private [16 rows][80B]

    // ---- biases -> LDS (consumed before the syncthreads drains vmcnt) ----
    if (tid < HD2) b1s[tid] = b1l[tid];
    __syncthreads();

    // ---- A slice in registers: a[kk] = A-frag for k-step kk (K=256) ----
    const ushort_t* Arow = A + (size_t)(row0 + w * 16 + lm) * HD;
    s8v a[8];
#pragma unroll
    for (int kk = 0; kk < 8; ++kk)
        a[kk] = *(const s8v*)(Arow + kk * 32 + q * 8);
    __builtin_amdgcn_s_waitcnt(WAITCNT_VM0);   // a[] resident; vmcnt clean

    // stage chunk cc into buf: 32 contiguous 1KB units, 4 per wave.
#define STAGE_W(buf, cc) do {                                                 \
    ushort_t* Wb_ = lds + (buf) * 16384;                                      \
    if (w < 4) {                                                              \
        _Pragma("unroll")                                                     \
        for (int i_ = 0; i_ < 4; ++i_) {                                      \
            const int u_ = w * 4 + i_;                                        \
            GLOAD_LDS16(W1l + ((cc) * 16 + u_) * 512 + L * 8,                 \
                        Wb_ + u_ * 512);                                      \
        }                                                                     \
    } else {                                                                  \
        _Pragma("unroll")                                                     \
        for (int i_ = 0; i_ < 4; ++i_) {                                      \
            const int u_ = (w - 4) * 4 + i_;                                  \
            GLOAD_LDS16(W2l + ((cc) * 16 + u_) * 512 + L * 8,                 \
                        Wb_ + 8192 + u_ * 512);                               \
        }                                                                     \
    }                                                                         \
} while (0)

    STAGE_W(0, 0);
    STAGE_W(1, 1);

    f4v acc2[16] = {};                   // z rows w*16.. x 256 cols
    for (int c = 0; c < 16; ++c) {
        if (c < 15) __builtin_amdgcn_s_waitcnt(WAITCNT_VM4);
        else        __builtin_amdgcn_s_waitcnt(WAITCNT_VM0);
        __builtin_amdgcn_s_barrier();
        __builtin_amdgcn_sched_barrier(0);

        const ushort_t* Wb  = lds + (c & 1) * 16384;
        const ushort_t* W2b = Wb + 8192;

        // GEMM1: hchunk = A x W1c  (2 chains x 8 deep)
        f4v acc1[2] = {};
        __builtin_amdgcn_s_setprio(1);
#pragma unroll
        for (int kk = 0; kk < 8; ++kk) {
#pragma unroll
            for (int nt = 0; nt < 2; ++nt) {
                s8v b = *(const s8v*)&Wb[(kk * 2 + nt) * 512 + L * 8];
                acc1[nt] = __builtin_amdgcn_mfma_f32_16x16x32_bf16(a[kk], b, acc1[nt], 0, 0, 0);
            }
        }
        __builtin_amdgcn_s_setprio(0);

        // bias + relu + bf16 -> wave-private LDS [16][80B] (frag transpose)
#pragma unroll
        for (int nt = 0; nt < 2; ++nt) {
            const float bj = b1s[c * 32 + nt * 16 + lm];
#pragma unroll
            for (int r = 0; r < 4; ++r) {
                const int rr = q * 4 + r;
                *(ushort_t*)(hcb + rr * 80 + (nt * 16 + lm) * 2) =
                    f2bf(fmaxf(acc1[nt][r] + bj, 0.f));
            }
        }
        // GEMM2: zacc += hchunk x W2c  (16 independent 1-deep chains)
        const s8v at = *(const s8v*)(hcb + lm * 80 + q * 16);
        __builtin_amdgcn_s_setprio(1);
#pragma unroll
        for (int nt = 0; nt < 16; ++nt) {
            s8v b = *(const s8v*)&W2b[nt * 512 + L * 8];
            acc2[nt] = __builtin_amdgcn_mfma_f32_16x16x32_bf16(at, b, acc2[nt], 0, 0, 0);
        }
        __builtin_amdgcn_s_setprio(0);

        __builtin_amdgcn_sched_barrier(0);
        __builtin_amdgcn_s_barrier();
        if (c + 2 < 16) STAGE_W((c & 1), c + 2);
    }
#undef STAGE_W

    __syncthreads();

    // ---- epilogue: bias + stats + bf16, LDS bounce for coalesced store ----
    ushort_t* Cs = lds;                      // [128][256] bf16, 64KB
    float* ssum  = (float*)(smem + 65536);   // [8][256]
    float* ssq   = (float*)(smem + 73728);   // [8][256]

#pragma unroll
    for (int nt = 0; nt < 16; ++nt) {
        const float bj = b2l[nt * 16 + lm];
        float s = 0.f, sq = 0.f;
#pragma unroll
        for (int r = 0; r < 4; ++r) {
            const float f  = acc2[nt][r] + bj;
            const int row  = w * 16 + q * 4 + r;
            Cs[row * 256 + nt * 16 + lm] = f2bf(f);
            if (row0 + row < NN) { s += f; sq += f * f; }
        }
        s  += __shfl_xor(s, 16, 64);  s  += __shfl_xor(s, 32, 64);
        sq += __shfl_xor(sq, 16, 64); sq += __shfl_xor(sq, 32, 64);
        if (q == 0) {
            ssum[w * 256 + nt * 16 + lm] = s;
            ssq [w * 256 + nt * 16 + lm] = sq;
        }
    }
    __syncthreads();

#pragma unroll
    for (int i = 0; i < 8; ++i) {
        const int idx = i * 512 + tid;       // 16B unit among 4096
        const int row = idx >> 5, ch = idx & 31;
        const s8v v = *(const s8v*)&Cs[idx * 8];
        *(s8v*)(C + (size_t)(row0 + row) * HD + ch * 8) = v;
    }
    if (tid < HD) {
        float s = 0.f, sq = 0.f;
#pragma unroll
        for (int ww = 0; ww < 8; ++ww) {
            s  += ssum[ww * 256 + tid];
            sq += ssq [ww * 256 + tid];
        }
        unsafeAtomicAdd(&stats[tid], s);
        unsafeAtomicAdd(&stats[HD + tid], sq);
    }
}

__global__ __launch_bounds__(256) void zero_kernel(float* __restrict__ p, long n4)
{
    const long i = (long)blockIdx.x * 256 + threadIdx.x;
    if (i < n4) ((float4*)p)[i] = make_float4(0.f, 0.f, 0.f, 0.f);
}

// zero all NL per-layer stats slots (2*HD floats each), once per call
__global__ __launch_bounds__(256) void init_stats_kernel(float* __restrict__ stats)
{
    const int t = threadIdx.x;
#pragma unroll
    for (int i = 0; i < 2 * NL; ++i) stats[i * HD + t] = 0.f;
}

// ---------------- CSR build (per call; edges are layer-invariant) -----------
__global__ __launch_bounds__(256) void hist_kernel(
    const int* __restrict__ dst, int* __restrict__ deg, int E)
{
    const int e = blockIdx.x * 256 + threadIdx.x;
    if (e < E) atomicAdd(&deg[dst[e]], 1);
}

__global__ __launch_bounds__(256) void scan1_kernel(
    const int* __restrict__ deg, int* __restrict__ partial,
    int* __restrict__ bsums, int n)
{
    __shared__ int tmp[256];
    const int i = blockIdx.x * 256 + threadIdx.x;
    const int v = (i < n) ? deg[i] : 0;
    tmp[threadIdx.x] = v;
    __syncthreads();
    for (int off = 1; off < 256; off <<= 1) {
        const int t = (threadIdx.x >= off) ? tmp[threadIdx.x - off] : 0;
        __syncthreads();
        tmp[threadIdx.x] += t;
        __syncthreads();
    }
    if (i < n) partial[i] = tmp[threadIdx.x] - v;
    if (threadIdx.x == 255) bsums[blockIdx.x] = tmp[255];
}

__global__ __launch_bounds__(512) void scan2_kernel(int* __restrict__ bsums, int nb)
{
    __shared__ int tmp[512];
    const int i = threadIdx.x;
    const int v = (i < nb) ? bsums[i] : 0;
    tmp[i] = v;
    __syncthreads();
    for (int off = 1; off < 512; off <<= 1) {
        const int t = (i >= off) ? tmp[i - off] : 0;
        __syncthreads();
        tmp[i] += t;
        __syncthreads();
    }
    if (i < nb) bsums[i] = tmp[i] - v;
}

__global__ __launch_bounds__(256) void scan3_kernel(
    const int* __restrict__ partial, const int* __restrict__ bsums,
    int* __restrict__ offs, int* __restrict__ cursor, int n)
{
    const int i = blockIdx.x * 256 + threadIdx.x;
    if (i < n) {
        const int o = partial[i] + bsums[blockIdx.x];
        offs[i] = o;
        cursor[i] = o;
    }
}

__global__ __launch_bounds__(256) void scatter_kernel(
    const int* __restrict__ src, const int* __restrict__ dst,
    int* __restrict__ cursor, int* __restrict__ srcSorted, int E)
{
    const int e = blockIdx.x * 256 + threadIdx.x;
    if (e >= E) return;
    const int p = atomicAdd(&cursor[dst[e]], 1);
    srcSorted[p] = src[e];
}

// ---------------------------------------------------------------------------
// Aggregate v2: out[n] = bf16( (1+eps)*y[n] + sum_{s in nbrs(n)} y[s] ),
// y[i] = relu( z[i]*sc + sh ) with (sc,sh) computed in-block from the
// previous layer's stats slot (statsPrev==null => identity: post-inproj z
// is already relu'd, so relu is idempotent).
//
// vs v1: ONE WAVE PER NODE. The two half-waves take alternating EDGES of the
// same node (trip counts differ by <=1 -> convergent exec), combined with a
// single shfl_xor(32). v1 put two different nodes on the two halves, so the
// wave looped max(ceil(dA/2),ceil(dB/2)) iters with divergent masks.
// ---------------------------------------------------------------------------
__global__ __launch_bounds__(512) void aggregate_kernel(
    const ushort_t* __restrict__ z, const int* __restrict__ offs,
    const int* __restrict__ deg, const int* __restrict__ srcSorted,
    const float* __restrict__ epsArr, int epsIdx,
    const float* __restrict__ statsPrev,   // [2*HD] or null (identity BN)
    const float* __restrict__ gammaPrev, const float* __restrict__ betaPrev,
    ushort_t* __restrict__ out)
{
    __shared__ float ssc[HD];
    __shared__ float ssh[HD];
    const int t = threadIdx.x;
    if (t < HD) {
        float sc = 1.f, sh = 0.f;
        if (statsPrev) {
            const float invN = 1.0f / (float)NN;
            const float mu  = statsPrev[t] * invN;
            const float var = statsPrev[HD + t] * invN - mu * mu;
            const float inv = rsqrtf(var + BN_EPS);
            sc = gammaPrev[t] * inv;
            sh = betaPrev[t] - mu * sc;
        }
        ssc[t] = sc;
        ssh[t] = sh;
    }
    __syncthreads();

    const int n = blockIdx.x * 8 + (t >> 6);   // wave per node; NN%8==0
    const int L = t & 63;
    const int h = L >> 5;                      // half-wave = edge parity
    const int c0 = (L & 31) * 8;
    const float4 scA = *(const float4*)(ssc + c0);
    const float4 scB = *(const float4*)(ssc + c0 + 4);
    const float4 shA = *(const float4*)(ssh + c0);
    const float4 shB = *(const float4*)(ssh + c0 + 4);
    const int start = offs[n];
    const int dc = deg[n];
    float a[8] = {};
    float b[8] = {};
    // half h takes edges {h, h+2, h+4, ...}; 2-deep unroll for MLP
    int j = h;
    for (; j + 2 < dc; j += 4) {
        const int s0 = srcSorted[start + j];
        const int s1 = srcSorted[start + j + 2];
        const uint4 u = *(const uint4*)(z + (size_t)s0 * HD + c0);
        const uint4 v = *(const uint4*)(z + (size_t)s1 * HD + c0);
        gacc(a, u, scA, scB, shA, shB, 1.f);
        gacc(b, v, scA, scB, shA, shB, 1.f);
    }
    if (j < dc) {
        const int s0 = srcSorted[start + j];
        const uint4 u = *(const uint4*)(z + (size_t)s0 * HD + c0);
        gacc(a, u, scA, scB, shA, shB, 1.f);
    }
#pragma unroll
    for (int k = 0; k < 8; ++k) a[k] += b[k];
#pragma unroll
    for (int k = 0; k < 8; ++k) a[k] += __shfl_xor(a[k], 32, 64);

    // self term (both halves compute identically; half 0 stores)
    const float se = 1.0f + epsArr[epsIdx];
    const uint4 hs = *(const uint4*)(z + (size_t)n * HD + c0);
    float y[8];
#pragma unroll
    for (int k = 0; k < 8; ++k) y[k] = a[k];
    gacc(y, hs, scA, scB, shA, shB, se);
    if (h == 0) {
        uint4 o;
        o.x = (unsigned)f2bf(y[0]) | ((unsigned)f2bf(y[1]) << 16);
        o.y = (unsigned)f2bf(y[2]) | ((unsigned)f2bf(y[3]) << 16);
        o.z = (unsigned)f2bf(y[4]) | ((unsigned)f2bf(y[5]) << 16);
        o.w = (unsigned)f2bf(y[6]) | ((unsigned)f2bf(y[7]) << 16);
        *(uint4*)(out + (size_t)n * HD + c0) = o;
    }
}

// ---------------------------------------------------------------------------
// Fused mean-pool + head, BN scale/shift computed in-block from the last
// layer's stats slot.
__global__ __launch_bounds__(256) void pool_head_kernel(
    const ushort_t* __restrict__ z, const int* __restrict__ batch,
    const float* __restrict__ statsPrev,   // [2*HD] (layer NL-1)
    const float* __restrict__ gammaPrev, const float* __restrict__ betaPrev,
    const float* __restrict__ Wp1, const float* __restrict__ bp1,
    const float* __restrict__ Wp2, const float* __restrict__ bp2,
    float* __restrict__ out)
{
    __shared__ float ssc[HD];
    __shared__ float ssh[HD];
    __shared__ float poolw[4][HD];
    __shared__ float pool[HD];
    __shared__ float red[128];
    __shared__ int seg[2];
    const int g = blockIdx.x;
    const int t = threadIdx.x;
    const int w = t >> 6;
    const int L = t & 63;
    {
        const float invN = 1.0f / (float)NN;
        const float mu  = statsPrev[t] * invN;
        const float var = statsPrev[HD + t] * invN - mu * mu;
        const float inv = rsqrtf(var + BN_EPS);
        const float sc  = gammaPrev[t] * inv;
        ssc[t] = sc;
        ssh[t] = betaPrev[t] - mu * sc;
    }
    if (t == 0) {
        int lo = 0, hi = NN;
        while (lo < hi) { const int m = (lo + hi) >> 1; if (batch[m] < g) lo = m + 1; else hi = m; }
        seg[0] = lo;
        hi = NN;
        while (lo < hi) { const int m = (lo + hi) >> 1; if (batch[m] < g + 1) lo = m + 1; else hi = m; }
        seg[1] = lo;
    }
    __syncthreads();
    const int start = seg[0], end = seg[1];
    const int c0 = L * 4;
    const float4 sc = *(const float4*)(ssc + c0);
    const float4 sh = *(const float4*)(ssh + c0);
    float a0 = 0.f, a1 = 0.f, a2 = 0.f, a3 = 0.f;
    float b0 = 0.f, b1 = 0.f, b2 = 0.f, b3 = 0.f;
    int r = start + w;
    for (; r + 4 < end; r += 8) {
        const ushort4 u = *(const ushort4*)(z + (size_t)r * HD + c0);
        const ushort4 v = *(const ushort4*)(z + (size_t)(r + 4) * HD + c0);
        a0 += fmaxf(bf2f(u.x) * sc.x + sh.x, 0.f);
        a1 += fmaxf(bf2f(u.y) * sc.y + sh.y, 0.f);
        a2 += fmaxf(bf2f(u.z) * sc.z + sh.z, 0.f);
        a3 += fmaxf(bf2f(u.w) * sc.w + sh.w, 0.f);
        b0 += fmaxf(bf2f(v.x) * sc.x + sh.x, 0.f);
        b1 += fmaxf(bf2f(v.y) * sc.y + sh.y, 0.f);
        b2 += fmaxf(bf2f(v.z) * sc.z + sh.z, 0.f);
        b3 += fmaxf(bf2f(v.w) * sc.w + sh.w, 0.f);
    }
    if (r < end) {
        const ushort4 u = *(const ushort4*)(z + (size_t)r * HD + c0);
        a0 += fmaxf(bf2f(u.x) * sc.x + sh.x, 0.f);
        a1 += fmaxf(bf2f(u.y) * sc.y + sh.y, 0.f);
        a2 += fmaxf(bf2f(u.z) * sc.z + sh.z, 0.f);
        a3 += fmaxf(bf2f(u.w) * sc.w + sh.w, 0.f);
    }
    poolw[w][c0 + 0] = a0 + b0;
    poolw[w][c0 + 1] = a1 + b1;
    poolw[w][c0 + 2] = a2 + b2;
    poolw[w][c0 + 3] = a3 + b3;
    __syncthreads();
    const float invC = 1.0f / (float)max(end - start, 1);
    pool[t] = (poolw[0][t] + poolw[1][t] + poolw[2][t] + poolw[3][t]) * invC;
    __syncthreads();
    if (t < 128) {
        float acc = 0.f;
#pragma unroll 4
        for (int k = 0; k < HD; ++k)
            acc += pool[k] * Wp1[k * 128 + t];
        red[t] = fmaxf(acc + bp1[t], 0.f) * Wp2[t];
    }
    __syncthreads();
    for (int sft = 64; sft > 0; sft >>= 1) {
        if (t < sft) red[t] += red[t + sft];
        __syncthreads();
    }
    if (t == 0) out[g] = red[0] + bp2[0];
}

// ---------------------------------------------------------------------------
extern "C" void kernel_launch(void* const* d_in, const int* in_sizes, int n_in,
                              void* d_out, int out_size, void* d_ws, size_t ws_size,
                              hipStream_t stream)
{
    const float* x     = (const float*)d_in[0];
    const int*   ei    = (const int*)  d_in[1];
    const int*   batch = (const int*)  d_in[2];
    const float* W_in  = (const float*)d_in[3];
    const float* b_in  = (const float*)d_in[4];
    const float* eps   = (const float*)d_in[5];
    const float* W1    = (const float*)d_in[6];
    const float* b1    = (const float*)d_in[7];
    const float* W2    = (const float*)d_in[8];
    const float* b2    = (const float*)d_in[9];
    const float* gamma = (const float*)d_in[10];
    const float* beta  = (const float*)d_in[11];
    const float* Wp1   = (const float*)d_in[12];
    const float* bp1   = (const float*)d_in[13];
    const float* Wp2   = (const float*)d_in[14];
    const float* bp2   = (const float*)d_in[15];

    const int* srcIdx = ei;
    const int* dstIdx = ei + EE;

    // ---- workspace layout ----
    char* p = (char*)d_ws;
    ushort_t* zbuf    = (ushort_t*)p;  p += (size_t)NP * HD  * 2;   // pre-BN acts
    ushort_t* abuf    = (ushort_t*)p;  p += (size_t)NP * HD  * 2;   // aggregate out
    ushort_t* W1P     = (ushort_t*)p;  p += (size_t)NL * HD2 * HD * 2;   // packed
    ushort_t* W2P     = (ushort_t*)p;  p += (size_t)NL * HD * HD2 * 2;   // packed
    ushort_t* WinP    = (ushort_t*)p;  p += (size_t)HD * DIN * 2;        // packed
    int* deg          = (int*)p;       p += (size_t)NN * 4;
    int* partial      = (int*)p;       p += (size_t)NN * 4;
    int* bsums        = (int*)p;       p += 512 * 4;
    int* offs         = (int*)p;       p += (size_t)NN * 4;
    int* cursor       = (int*)p;       p += (size_t)NN * 4;
    int* srcSorted    = (int*)p;       p += (size_t)EE * 4;
    float* stats      = (float*)p;     p += (size_t)NL * 2 * HD * 4;  // per-layer slots

    const int nb = (NN + 255) / 256;   // 391
    const int INPROJ_LDS = 65536;      // inproj: 64KB W (epilogue-overlaid)
    const int FUSED_LDS  = 81920;      // fused_mlp v2: 2x32KB W + hchunk + bias

    // ---- stats slots zero ----
    init_stats_kernel<<<1, 256, 0, stream>>>(stats);

    // ---- weight conversion (all packed MFMA-frag order) ----
    pack_win_kernel<<<16, 256, 0, stream>>>(W_in, WinP);
    pack_w1_kernel<<<256, 256, 0, stream>>>(W1, W1P);
    pack_w2_kernel<<<256, 256, 0, stream>>>(W2, W2P);

    // ---- CSR build (once; edges layer-invariant) ----
    zero_kernel<<<(NN / 4 + 255) / 256, 256, 0, stream>>>((float*)deg, NN / 4);
    hist_kernel<<<(EE + 255) / 256, 256, 0, stream>>>(dstIdx, deg, EE);
    scan1_kernel<<<nb, 256, 0, stream>>>(deg, partial, bsums, NN);
    scan2_kernel<<<1, 512, 0, stream>>>(bsums, nb);
    scan3_kernel<<<nb, 256, 0, stream>>>(partial, bsums, offs, cursor, NN);
    scatter_kernel<<<(EE + 255) / 256, 256, 0, stream>>>(srcIdx, dstIdx, cursor, srcSorted, EE);

    // ---- input projection: zbuf = relu(x @ W_in + b_in), x read as f32 ----
    inproj_kernel<<<NP / 128, 512, INPROJ_LDS, stream>>>(x, WinP, b_in, zbuf);

    // ---- GIN layers: aggregate (BN in-block) -> fused MLP (+stats slot) ----
    for (int l = 0; l < NL; ++l) {
        const float* sp = (l == 0) ? nullptr : stats + (size_t)(l - 1) * 2 * HD;
        aggregate_kernel<<<NN / 8, 512, 0, stream>>>(
            zbuf, offs, deg, srcSorted, eps, l,
            sp, gamma + (size_t)(l - 1 < 0 ? 0 : l - 1) * HD,
            beta + (size_t)(l - 1 < 0 ? 0 : l - 1) * HD, abuf);

        fused_mlp_kernel<<<NP / 128, 512, FUSED_LDS, stream>>>(
            abuf, W1P + (size_t)l * HD2 * HD, b1 + (size_t)l * HD2,
            W2P + (size_t)l * HD * HD2, b2 + (size_t)l * HD, zbuf,
            stats + (size_t)l * 2 * HD);
    }

    // ---- fused mean pool + head (BN from layer NL-1 stats slot) ----
    pool_head_kernel<<<NG, 256, 0, stream>>>(
        zbuf, batch, stats + (size_t)(NL - 1) * 2 * HD,
        gamma + (size_t)(NL - 1) * HD, beta + (size_t)(NL - 1) * HD,
        Wp1, bp1, Wp2, bp2, (float*)d_out);
}

// Round 9
// 719.380 us; speedup vs baseline: 1.0888x; 1.0888x over previous
//
#include <hip/hip_runtime.h>

#define NN 100000
#define NP 100096          // 782 * 128, padded row count
#define EE 300000
#define DIN 128
#define HD  256
#define HD2 512
#define NL  4
#define NG  512
#define BN_EPS 1e-5f

typedef __attribute__((ext_vector_type(8))) short s8v;      // bf16x8 frag (4 VGPRs)
typedef __attribute__((ext_vector_type(4))) float f4v;      // fp32x4 acc

typedef unsigned short ushort_t;

// float -> bf16, round-to-nearest-even
static __device__ inline ushort_t f2bf(float f) {
    unsigned u = __float_as_uint(f);
    unsigned r = (u + 0x7fffu + ((u >> 16) & 1u)) >> 16;
    return (ushort_t)r;
}
static __device__ inline float bf2f(ushort_t h) {
    return __uint_as_float(((unsigned)h) << 16);
}
// bf16 pair unpack from packed u32: low half needs shift, high half mask-only
static __device__ inline float blo(unsigned v) { return __uint_as_float(v << 16); }
static __device__ inline float bhi(unsigned v) { return __uint_as_float(v & 0xffff0000u); }

// accumulate 8 channels of BN+relu'd row segment: A[i] += wg * relu(z*sc+sh)
static __device__ inline void gacc(float* A, const uint4 u,
                                   const float4 s0, const float4 s1,
                                   const float4 h0, const float4 h1, float wg) {
    A[0] += wg * fmaxf(blo(u.x) * s0.x + h0.x, 0.f);
    A[1] += wg * fmaxf(bhi(u.x) * s0.y + h0.y, 0.f);
    A[2] += wg * fmaxf(blo(u.y) * s0.z + h0.z, 0.f);
    A[3] += wg * fmaxf(bhi(u.y) * s0.w + h0.w, 0.f);
    A[4] += wg * fmaxf(blo(u.z) * s1.x + h1.x, 0.f);
    A[5] += wg * fmaxf(bhi(u.z) * s1.y + h1.y, 0.f);
    A[6] += wg * fmaxf(blo(u.w) * s1.z + h1.z, 0.f);
    A[7] += wg * fmaxf(bhi(u.w) * s1.w + h1.w, 0.f);
}

// async global->LDS, 16B per lane; LDS dest = uniform base + lane*16
#define GLOAD_LDS16(g, l) __builtin_amdgcn_global_load_lds( \
    (const __attribute__((address_space(1))) unsigned int*)(const void*)(g), \
    (__attribute__((address_space(3))) unsigned int*)(void*)(l), 16, 0, 0)

// s_waitcnt immediates: vmcnt[3:0] | expcnt(7)<<4 | lgkmcnt(15)<<8 | vmcnt[5:4]<<14
#define WAITCNT_VM8 0xF78
#define WAITCNT_VM4 0xF74
#define WAITCNT_VM0 0xF70

// ---------------------------------------------------------------------------
// Weight packing into MFMA-fragment order so staging is contiguous 1KB
// bursts. Unit = 1KB = [lane L][e 0..7] bf16.
// W1 input [NL][HD][HD2] f32 (in x out). Unit (l, c, u): kk=u>>1, nt=u&1;
//   value = W1[l][kk*32 + (L>>4)*8 + e][c*32 + nt*16 + (L&15)].
__global__ __launch_bounds__(256) void pack_w1_kernel(
    const float* __restrict__ W1, ushort_t* __restrict__ W1P)
{
    const int t = threadIdx.x, L = t & 63;
    const int gu = blockIdx.x * 4 + (t >> 6);      // 0..1023
    const int l = gu >> 8, rem = gu & 255;
    const int c = rem >> 4, u = rem & 15;
    const int kk = u >> 1, nt = u & 1;
    const int h  = c * 32 + nt * 16 + (L & 15);
    const int k0 = kk * 32 + (L >> 4) * 8;
    const float* src = W1 + (size_t)l * HD * HD2;
    s8v v;
#pragma unroll
    for (int e = 0; e < 8; ++e)
        v[e] = (short)f2bf(src[(size_t)(k0 + e) * HD2 + h]);
    *(s8v*)(W1P + (size_t)gu * 512 + L * 8) = v;
}

// W2 input [NL][HD2][HD] f32. Unit (l, c, nt):
//   value = W2[l][c*32 + (L>>4)*8 + e][nt*16 + (L&15)].
__global__ __launch_bounds__(256) void pack_w2_kernel(
    const float* __restrict__ W2, ushort_t* __restrict__ W2P)
{
    const int t = threadIdx.x, L = t & 63;
    const int gu = blockIdx.x * 4 + (t >> 6);      // 0..1023
    const int l = gu >> 8, rem = gu & 255;
    const int c = rem >> 4, nt = rem & 15;
    const int h  = nt * 16 + (L & 15);
    const int k0 = c * 32 + (L >> 4) * 8;
    const float* src = W2 + (size_t)l * HD2 * HD;
    s8v v;
#pragma unroll
    for (int e = 0; e < 8; ++e)
        v[e] = (short)f2bf(src[(size_t)(k0 + e) * HD + h]);
    *(s8v*)(W2P + (size_t)gu * 512 + L * 8) = v;
}

// W_in input [DIN][HD] f32 (in x out), 64 units (kk=u>>4 in [0,4), nt=u&15):
//   value = Win[kk*32 + (L>>4)*8 + e][nt*16 + (L&15)].
__global__ __launch_bounds__(256) void pack_win_kernel(
    const float* __restrict__ Win, ushort_t* __restrict__ WinP)
{
    const int t = threadIdx.x, L = t & 63;
    const int gu = blockIdx.x * 4 + (t >> 6);      // 0..63
    const int kk = gu >> 4, nt = gu & 15;
    const int h  = nt * 16 + (L & 15);
    const int k0 = kk * 32 + (L >> 4) * 8;
    s8v v;
#pragma unroll
    for (int e = 0; e < 8; ++e)
        v[e] = (short)f2bf(Win[(size_t)(k0 + e) * HD + h]);
    *(s8v*)(WinP + (size_t)gu * 512 + L * 8) = v;
}

// ---------------------------------------------------------------------------
// Input projection: z = relu(x @ W_in + b_in). W_in (64KB packed) is fully
// LDS-resident: stage once, no inner barriers, 64 MFMAs/wave. Reads x in f32
// directly (in-register cvt).
// ---------------------------------------------------------------------------
__global__ __launch_bounds__(512, 2) void inproj_kernel(
    const float* __restrict__ x,        // [NN, DIN] f32
    const ushort_t* __restrict__ WinP,  // [64 units x 512] packed bf16
    const float* __restrict__ bias,     // [HD]
    ushort_t* __restrict__ C)           // [NP, HD] bf16
{
    extern __shared__ char smem[];
    ushort_t* Ws = (ushort_t*)smem;     // 64 KB, epilogue-overlaid as Cs
    const int tid = threadIdx.x;
    const int w   = tid >> 6;
    const int L   = tid & 63;
    const int lm  = L & 15;
    const int q   = L >> 4;
    const int row0 = blockIdx.x * 128;

    // stage all 64 weight units (8 per wave), one contiguous 1KB burst each
#pragma unroll
    for (int i = 0; i < 8; ++i) {
        const int u = w * 8 + i;
        GLOAD_LDS16(WinP + u * 512 + L * 8, Ws + u * 512);
    }

    // A-frags from x (f32 -> bf16 in-register); clamp padded rows
    const int row = row0 + w * 16 + lm;
    const float* xr = x + (size_t)min(row, NN - 1) * DIN;
    s8v a[4];
#pragma unroll
    for (int kk = 0; kk < 4; ++kk) {
        const float4 u0 = *(const float4*)(xr + kk * 32 + q * 8);
        const float4 u1 = *(const float4*)(xr + kk * 32 + q * 8 + 4);
        s8v v;
        v[0] = (short)f2bf(u0.x); v[1] = (short)f2bf(u0.y);
        v[2] = (short)f2bf(u0.z); v[3] = (short)f2bf(u0.w);
        v[4] = (short)f2bf(u1.x); v[5] = (short)f2bf(u1.y);
        v[6] = (short)f2bf(u1.z); v[7] = (short)f2bf(u1.w);
        a[kk] = v;
    }
    __builtin_amdgcn_s_waitcnt(WAITCNT_VM0);
    __syncthreads();

    f4v acc[16] = {};
#pragma unroll
    for (int kk = 0; kk < 4; ++kk) {
#pragma unroll
        for (int nt = 0; nt < 16; ++nt) {
            s8v b = *(const s8v*)&Ws[(kk * 16 + nt) * 512 + L * 8];
            acc[nt] = __builtin_amdgcn_mfma_f32_16x16x32_bf16(a[kk], b, acc[nt], 0, 0, 0);
        }
    }
    __syncthreads();

    // epilogue: bias + relu + bf16 via LDS bounce for coalesced 16B stores
    ushort_t* Cs = Ws;
#pragma unroll
    for (int nt = 0; nt < 16; ++nt) {
        const float bj = bias[nt * 16 + lm];
#pragma unroll
        for (int r = 0; r < 4; ++r) {
            const int rr = w * 16 + q * 4 + r;
            Cs[rr * 256 + nt * 16 + lm] = f2bf(fmaxf(acc[nt][r] + bj, 0.f));
        }
    }
    __syncthreads();
#pragma unroll
    for (int i = 0; i < 8; ++i) {
        const int idx = i * 512 + tid;       // 16B unit among 4096
        const int rr = idx >> 5, ch = idx & 31;
        const s8v v = *(const s8v*)&Cs[idx * 8];
        *(s8v*)(C + (size_t)(row0 + rr) * HD + ch * 8) = v;
    }
}

// ---------------------------------------------------------------------------
// Fused GIN MLP v2 (measured optimum — FROZEN):
// z = (agg @ W1 + b1).relu() @ W2 + b2, plus column stats (into a per-layer
// stats slot).
// ---------------------------------------------------------------------------
__global__ __launch_bounds__(512, 4) void fused_mlp_kernel(
    const ushort_t* __restrict__ A,      // [NP, HD] bf16 (aggregate out)
    const ushort_t* __restrict__ W1l,    // [256 units x 512] packed bf16
    const float*    __restrict__ b1l,    // [HD2]
    const ushort_t* __restrict__ W2l,    // [256 units x 512] packed bf16
    const float*    __restrict__ b2l,    // [HD]
    ushort_t* __restrict__ C,            // [NP, HD] bf16 (pre-BN z)
    float* __restrict__ stats)           // [2*HD] slot: col sum / sumsq
{
    extern __shared__ char smem[];
    ushort_t* lds = (ushort_t*)smem;
    const int tid = threadIdx.x;
    const int w   = tid >> 6;            // wave 0..7 -> rows [w*16, w*16+16)
    const int L   = tid & 63;
    const int lm  = L & 15;
    const int q   = L >> 4;
    const int row0 = blockIdx.x * 128;

    // LDS map (bytes): 0..32767 buf0 | 32768..65535 buf1 |
    // 65536..75775 hchunk (8 x 1280) | 75776..77823 b1s | rest spare.
    // Epilogue overlay: Cs 0..65535 | ssum 65536..73727 | ssq 73728..81919.
    float* b1s = (float*)(smem + 75776);
    char*  hcb = smem + 65536 + w * 1280;   // wave-private [16 rows][80B]

    // ---- biases -> LDS (consumed before the syncthreads drains vmcnt) ----
    if (tid < HD2) b1s[tid] = b1l[tid];
    __syncthreads();

    // ---- A slice in registers: a[kk] = A-frag for k-step kk (K=256) ----
    const ushort_t* Arow = A + (size_t)(row0 + w * 16 + lm) * HD;
    s8v a[8];
#pragma unroll
    for (int kk = 0; kk < 8; ++kk)
        a[kk] = *(const s8v*)(Arow + kk * 32 + q * 8);
    __builtin_amdgcn_s_waitcnt(WAITCNT_VM0);   // a[] resident; vmcnt clean

    // stage chunk cc into buf: 32 contiguous 1KB units, 4 per wave.
#define STAGE_W(buf, cc) do {                                                 \
    ushort_t* Wb_ = lds + (buf) * 16384;                                      \
    if (w < 4) {                                                              \
        _Pragma("unroll")                                                     \
        for (int i_ = 0; i_ < 4; ++i_) {                                      \
            const int u_ = w * 4 + i_;                                        \
            GLOAD_LDS16(W1l + ((cc) * 16 + u_) * 512 + L * 8,                 \
                        Wb_ + u_ * 512);                                      \
        }                                                                     \
    } else {                                                                  \
        _Pragma("unroll")                                                     \
        for (int i_ = 0; i_ < 4; ++i_) {                                      \
            const int u_ = (w - 4) * 4 + i_;                                  \
            GLOAD_LDS16(W2l + ((cc) * 16 + u_) * 512 + L * 8,                 \
                        Wb_ + 8192 + u_ * 512);                               \
        }                                                                     \
    }                                                                         \
} while (0)

    STAGE_W(0, 0);
    STAGE_W(1, 1);

    f4v acc2[16] = {};                   // z rows w*16.. x 256 cols
    for (int c = 0; c < 16; ++c) {
        if (c < 15) __builtin_amdgcn_s_waitcnt(WAITCNT_VM4);
        else        __builtin_amdgcn_s_waitcnt(WAITCNT_VM0);
        __builtin_amdgcn_s_barrier();
        __builtin_amdgcn_sched_barrier(0);

        const ushort_t* Wb  = lds + (c & 1) * 16384;
        const ushort_t* W2b = Wb + 8192;

        // GEMM1: hchunk = A x W1c  (2 chains x 8 deep)
        f4v acc1[2] = {};
        __builtin_amdgcn_s_setprio(1);
#pragma unroll
        for (int kk = 0; kk < 8; ++kk) {
#pragma unroll
            for (int nt = 0; nt < 2; ++nt) {
                s8v b = *(const s8v*)&Wb[(kk * 2 + nt) * 512 + L * 8];
                acc1[nt] = __builtin_amdgcn_mfma_f32_16x16x32_bf16(a[kk], b, acc1[nt], 0, 0, 0);
            }
        }
        __builtin_amdgcn_s_setprio(0);

        // bias + relu + bf16 -> wave-private LDS [16][80B] (frag transpose)
#pragma unroll
        for (int nt = 0; nt < 2; ++nt) {
            const float bj = b1s[c * 32 + nt * 16 + lm];
#pragma unroll
            for (int r = 0; r < 4; ++r) {
                const int rr = q * 4 + r;
                *(ushort_t*)(hcb + rr * 80 + (nt * 16 + lm) * 2) =
                    f2bf(fmaxf(acc1[nt][r] + bj, 0.f));
            }
        }
        // GEMM2: zacc += hchunk x W2c  (16 independent 1-deep chains)
        const s8v at = *(const s8v*)(hcb + lm * 80 + q * 16);
        __builtin_amdgcn_s_setprio(1);
#pragma unroll
        for (int nt = 0; nt < 16; ++nt) {
            s8v b = *(const s8v*)&W2b[nt * 512 + L * 8];
            acc2[nt] = __builtin_amdgcn_mfma_f32_16x16x32_bf16(at, b, acc2[nt], 0, 0, 0);
        }
        __builtin_amdgcn_s_setprio(0);

        __builtin_amdgcn_sched_barrier(0);
        __builtin_amdgcn_s_barrier();
        if (c + 2 < 16) STAGE_W((c & 1), c + 2);
    }
#undef STAGE_W

    __syncthreads();

    // ---- epilogue: bias + stats + bf16, LDS bounce for coalesced store ----
    ushort_t* Cs = lds;                      // [128][256] bf16, 64KB
    float* ssum  = (float*)(smem + 65536);   // [8][256]
    float* ssq   = (float*)(smem + 73728);   // [8][256]

#pragma unroll
    for (int nt = 0; nt < 16; ++nt) {
        const float bj = b2l[nt * 16 + lm];
        float s = 0.f, sq = 0.f;
#pragma unroll
        for (int r = 0; r < 4; ++r) {
            const float f  = acc2[nt][r] + bj;
            const int row  = w * 16 + q * 4 + r;
            Cs[row * 256 + nt * 16 + lm] = f2bf(f);
            if (row0 + row < NN) { s += f; sq += f * f; }
        }
        s  += __shfl_xor(s, 16, 64);  s  += __shfl_xor(s, 32, 64);
        sq += __shfl_xor(sq, 16, 64); sq += __shfl_xor(sq, 32, 64);
        if (q == 0) {
            ssum[w * 256 + nt * 16 + lm] = s;
            ssq [w * 256 + nt * 16 + lm] = sq;
        }
    }
    __syncthreads();

#pragma unroll
    for (int i = 0; i < 8; ++i) {
        const int idx = i * 512 + tid;       // 16B unit among 4096
        const int row = idx >> 5, ch = idx & 31;
        const s8v v = *(const s8v*)&Cs[idx * 8];
        *(s8v*)(C + (size_t)(row0 + row) * HD + ch * 8) = v;
    }
    if (tid < HD) {
        float s = 0.f, sq = 0.f;
#pragma unroll
        for (int ww = 0; ww < 8; ++ww) {
            s  += ssum[ww * 256 + tid];
            sq += ssq [ww * 256 + tid];
        }
        unsafeAtomicAdd(&stats[tid], s);
        unsafeAtomicAdd(&stats[HD + tid], sq);
    }
}

__global__ __launch_bounds__(256) void zero_kernel(float* __restrict__ p, long n4)
{
    const long i = (long)blockIdx.x * 256 + threadIdx.x;
    if (i < n4) ((float4*)p)[i] = make_float4(0.f, 0.f, 0.f, 0.f);
}

// zero all NL per-layer stats slots (2*HD floats each), once per call
__global__ __launch_bounds__(256) void init_stats_kernel(float* __restrict__ stats)
{
    const int t = threadIdx.x;
#pragma unroll
    for (int i = 0; i < 2 * NL; ++i) stats[i * HD + t] = 0.f;
}

// ---------------- CSR build (per call; edges are layer-invariant) -----------
__global__ __launch_bounds__(256) void hist_kernel(
    const int* __restrict__ dst, int* __restrict__ deg, int E)
{
    const int e = blockIdx.x * 256 + threadIdx.x;
    if (e < E) atomicAdd(&deg[dst[e]], 1);
}

__global__ __launch_bounds__(256) void scan1_kernel(
    const int* __restrict__ deg, int* __restrict__ partial,
    int* __restrict__ bsums, int n)
{
    __shared__ int tmp[256];
    const int i = blockIdx.x * 256 + threadIdx.x;
    const int v = (i < n) ? deg[i] : 0;
    tmp[threadIdx.x] = v;
    __syncthreads();
    for (int off = 1; off < 256; off <<= 1) {
        const int t = (threadIdx.x >= off) ? tmp[threadIdx.x - off] : 0;
        __syncthreads();
        tmp[threadIdx.x] += t;
        __syncthreads();
    }
    if (i < n) partial[i] = tmp[threadIdx.x] - v;
    if (threadIdx.x == 255) bsums[blockIdx.x] = tmp[255];
}

__global__ __launch_bounds__(512) void scan2_kernel(int* __restrict__ bsums, int nb)
{
    __shared__ int tmp[512];
    const int i = threadIdx.x;
    const int v = (i < nb) ? bsums[i] : 0;
    tmp[i] = v;
    __syncthreads();
    for (int off = 1; off < 512; off <<= 1) {
        const int t = (i >= off) ? tmp[i - off] : 0;
        __syncthreads();
        tmp[i] += t;
        __syncthreads();
    }
    if (i < nb) bsums[i] = tmp[i] - v;
}

__global__ __launch_bounds__(256) void scan3_kernel(
    const int* __restrict__ partial, const int* __restrict__ bsums,
    int* __restrict__ offs, int* __restrict__ cursor, int n)
{
    const int i = blockIdx.x * 256 + threadIdx.x;
    if (i < n) {
        const int o = partial[i] + bsums[blockIdx.x];
        offs[i] = o;
        cursor[i] = o;
    }
}

__global__ __launch_bounds__(256) void scatter_kernel(
    const int* __restrict__ src, const int* __restrict__ dst,
    int* __restrict__ cursor, int* __restrict__ srcSorted, int E)
{
    const int e = blockIdx.x * 256 + threadIdx.x;
    if (e >= E) return;
    const int p = atomicAdd(&cursor[dst[e]], 1);
    srcSorted[p] = src[e];
}

// ---------------------------------------------------------------------------
// Aggregate (v1 structure RESTORED — 2 nodes per wave, 32 lanes/node; the
// measured-good round-0 loop) + in-block BN prep (ssc/ssh from the previous
// layer's stats slot; statsPrev==null => identity, inproj output already
// relu'd so relu is idempotent).
// out[n] = bf16( (1+eps)*y[n] + sum_{s in nbrs(n)} y[s] ), y = relu(z*sc+sh).
// ---------------------------------------------------------------------------
__global__ __launch_bounds__(256) void aggregate_kernel(
    const ushort_t* __restrict__ z, const int* __restrict__ offs,
    const int* __restrict__ deg, const int* __restrict__ srcSorted,
    const float* __restrict__ epsArr, int epsIdx,
    const float* __restrict__ statsPrev,   // [2*HD] or null (identity BN)
    const float* __restrict__ gammaPrev, const float* __restrict__ betaPrev,
    ushort_t* __restrict__ out)
{
    __shared__ float ssc[HD];
    __shared__ float ssh[HD];
    const int t = threadIdx.x;
    {
        float sc = 1.f, sh = 0.f;
        if (statsPrev) {
            const float invN = 1.0f / (float)NN;
            const float mu  = statsPrev[t] * invN;
            const float var = statsPrev[HD + t] * invN - mu * mu;
            const float inv = rsqrtf(var + BN_EPS);
            sc = gammaPrev[t] * inv;
            sh = betaPrev[t] - mu * sc;
        }
        ssc[t] = sc;
        ssh[t] = sh;
    }
    __syncthreads();

    const int n = blockIdx.x * 8 + (t >> 5);   // 8 nodes / 256 thr
    const int L = t & 31;
    const int c0 = L * 8;
    const float4 scA = *(const float4*)(ssc + c0);
    const float4 scB = *(const float4*)(ssc + c0 + 4);
    const float4 shA = *(const float4*)(ssh + c0);
    const float4 shB = *(const float4*)(ssh + c0 + 4);
    const int start = offs[n];
    const int dc = deg[n];
    float a[8] = {};
    float b[8] = {};
    int j = 0;
    for (; j + 1 < dc; j += 2) {
        const int s0 = srcSorted[start + j];
        const int s1 = srcSorted[start + j + 1];
        const uint4 u = *(const uint4*)(z + (size_t)s0 * HD + c0);
        const uint4 v = *(const uint4*)(z + (size_t)s1 * HD + c0);
        gacc(a, u, scA, scB, shA, shB, 1.f);
        gacc(b, v, scA, scB, shA, shB, 1.f);
    }
    if (j < dc) {
        const int s0 = srcSorted[start + j];
        const uint4 u = *(const uint4*)(z + (size_t)s0 * HD + c0);
        gacc(a, u, scA, scB, shA, shB, 1.f);
    }
#pragma unroll
    for (int k = 0; k < 8; ++k) a[k] += b[k];

    // self term, weight (1+eps)
    const float se = 1.0f + epsArr[epsIdx];
    const uint4 hs = *(const uint4*)(z + (size_t)n * HD + c0);
    gacc(a, hs, scA, scB, shA, shB, se);

    uint4 o;
    o.x = (unsigned)f2bf(a[0]) | ((unsigned)f2bf(a[1]) << 16);
    o.y = (unsigned)f2bf(a[2]) | ((unsigned)f2bf(a[3]) << 16);
    o.z = (unsigned)f2bf(a[4]) | ((unsigned)f2bf(a[5]) << 16);
    o.w = (unsigned)f2bf(a[6]) | ((unsigned)f2bf(a[7]) << 16);
    *(uint4*)(out + (size_t)n * HD + c0) = o;
}

// ---------------------------------------------------------------------------
// Fused mean-pool + head, BN scale/shift computed in-block from the last
// layer's stats slot.
__global__ __launch_bounds__(256) void pool_head_kernel(
    const ushort_t* __restrict__ z, const int* __restrict__ batch,
    const float* __restrict__ statsPrev,   // [2*HD] (layer NL-1)
    const float* __restrict__ gammaPrev, const float* __restrict__ betaPrev,
    const float* __restrict__ Wp1, const float* __restrict__ bp1,
    const float* __restrict__ Wp2, const float* __restrict__ bp2,
    float* __restrict__ out)
{
    __shared__ float ssc[HD];
    __shared__ float ssh[HD];
    __shared__ float poolw[4][HD];
    __shared__ float pool[HD];
    __shared__ float red[128];
    __shared__ int seg[2];
    const int g = blockIdx.x;
    const int t = threadIdx.x;
    const int w = t >> 6;
    const int L = t & 63;
    {
        const float invN = 1.0f / (float)NN;
        const float mu  = statsPrev[t] * invN;
        const float var = statsPrev[HD + t] * invN - mu * mu;
        const float inv = rsqrtf(var + BN_EPS);
        const float sc  = gammaPrev[t] * inv;
        ssc[t] = sc;
        ssh[t] = betaPrev[t] - mu * sc;
    }
    if (t == 0) {
        int lo = 0, hi = NN;
        while (lo < hi) { const int m = (lo + hi) >> 1; if (batch[m] < g) lo = m + 1; else hi = m; }
        seg[0] = lo;
        hi = NN;
        while (lo < hi) { const int m = (lo + hi) >> 1; if (batch[m] < g + 1) lo = m + 1; else hi = m; }
        seg[1] = lo;
    }
    __syncthreads();
    const int start = seg[0], end = seg[1];
    const int c0 = L * 4;
    const float4 sc = *(const float4*)(ssc + c0);
    const float4 sh = *(const float4*)(ssh + c0);
    float a0 = 0.f, a1 = 0.f, a2 = 0.f, a3 = 0.f;
    float b0 = 0.f, b1 = 0.f, b2 = 0.f, b3 = 0.f;
    int r = start + w;
    for (; r + 4 < end; r += 8) {
        const ushort4 u = *(const ushort4*)(z + (size_t)r * HD + c0);
        const ushort4 v = *(const ushort4*)(z + (size_t)(r + 4) * HD + c0);
        a0 += fmaxf(bf2f(u.x) * sc.x + sh.x, 0.f);
        a1 += fmaxf(bf2f(u.y) * sc.y + sh.y, 0.f);
        a2 += fmaxf(bf2f(u.z) * sc.z + sh.z, 0.f);
        a3 += fmaxf(bf2f(u.w) * sc.w + sh.w, 0.f);
        b0 += fmaxf(bf2f(v.x) * sc.x + sh.x, 0.f);
        b1 += fmaxf(bf2f(v.y) * sc.y + sh.y, 0.f);
        b2 += fmaxf(bf2f(v.z) * sc.z + sh.z, 0.f);
        b3 += fmaxf(bf2f(v.w) * sc.w + sh.w, 0.f);
    }
    if (r < end) {
        const ushort4 u = *(const ushort4*)(z + (size_t)r * HD + c0);
        a0 += fmaxf(bf2f(u.x) * sc.x + sh.x, 0.f);
        a1 += fmaxf(bf2f(u.y) * sc.y + sh.y, 0.f);
        a2 += fmaxf(bf2f(u.z) * sc.z + sh.z, 0.f);
        a3 += fmaxf(bf2f(u.w) * sc.w + sh.w, 0.f);
    }
    poolw[w][c0 + 0] = a0 + b0;
    poolw[w][c0 + 1] = a1 + b1;
    poolw[w][c0 + 2] = a2 + b2;
    poolw[w][c0 + 3] = a3 + b3;
    __syncthreads();
    const float invC = 1.0f / (float)max(end - start, 1);
    pool[t] = (poolw[0][t] + poolw[1][t] + poolw[2][t] + poolw[3][t]) * invC;
    __syncthreads();
    if (t < 128) {
        float acc = 0.f;
#pragma unroll 4
        for (int k = 0; k < HD; ++k)
            acc += pool[k] * Wp1[k * 128 + t];
        red[t] = fmaxf(acc + bp1[t], 0.f) * Wp2[t];
    }
    __syncthreads();
    for (int sft = 64; sft > 0; sft >>= 1) {
        if (t < sft) red[t] += red[t + sft];
        __syncthreads();
    }
    if (t == 0) out[g] = red[0] + bp2[0];
}

// ---------------------------------------------------------------------------
extern "C" void kernel_launch(void* const* d_in, const int* in_sizes, int n_in,
                              void* d_out, int out_size, void* d_ws, size_t ws_size,
                              hipStream_t stream)
{
    const float* x     = (const float*)d_in[0];
    const int*   ei    = (const int*)  d_in[1];
    const int*   batch = (const int*)  d_in[2];
    const float* W_in  = (const float*)d_in[3];
    const float* b_in  = (const float*)d_in[4];
    const float* eps   = (const float*)d_in[5];
    const float* W1    = (const float*)d_in[6];
    const float* b1    = (const float*)d_in[7];
    const float* W2    = (const float*)d_in[8];
    const float* b2    = (const float*)d_in[9];
    const float* gamma = (const float*)d_in[10];
    const float* beta  = (const float*)d_in[11];
    const float* Wp1   = (const float*)d_in[12];
    const float* bp1   = (const float*)d_in[13];
    const float* Wp2   = (const float*)d_in[14];
    const float* bp2   = (const float*)d_in[15];

    const int* srcIdx = ei;
    const int* dstIdx = ei + EE;

    // ---- workspace layout ----
    char* p = (char*)d_ws;
    ushort_t* zbuf    = (ushort_t*)p;  p += (size_t)NP * HD  * 2;   // pre-BN acts
    ushort_t* abuf    = (ushort_t*)p;  p += (size_t)NP * HD  * 2;   // aggregate out
    ushort_t* W1P     = (ushort_t*)p;  p += (size_t)NL * HD2 * HD * 2;   // packed
    ushort_t* W2P     = (ushort_t*)p;  p += (size_t)NL * HD * HD2 * 2;   // packed
    ushort_t* WinP    = (ushort_t*)p;  p += (size_t)HD * DIN * 2;        // packed
    int* deg          = (int*)p;       p += (size_t)NN * 4;
    int* partial      = (int*)p;       p += (size_t)NN * 4;
    int* bsums        = (int*)p;       p += 512 * 4;
    int* offs         = (int*)p;       p += (size_t)NN * 4;
    int* cursor       = (int*)p;       p += (size_t)NN * 4;
    int* srcSorted    = (int*)p;       p += (size_t)EE * 4;
    float* stats      = (float*)p;     p += (size_t)NL * 2 * HD * 4;  // per-layer slots

    const int nb = (NN + 255) / 256;   // 391
    const int INPROJ_LDS = 65536;      // inproj: 64KB W (epilogue-overlaid)
    const int FUSED_LDS  = 81920;      // fused_mlp v2: 2x32KB W + hchunk + bias

    // ---- stats slots zero ----
    init_stats_kernel<<<1, 256, 0, stream>>>(stats);

    // ---- weight conversion (all packed MFMA-frag order) ----
    pack_win_kernel<<<16, 256, 0, stream>>>(W_in, WinP);
    pack_w1_kernel<<<256, 256, 0, stream>>>(W1, W1P);
    pack_w2_kernel<<<256, 256, 0, stream>>>(W2, W2P);

    // ---- CSR build (once; edges layer-invariant) ----
    zero_kernel<<<(NN / 4 + 255) / 256, 256, 0, stream>>>((float*)deg, NN / 4);
    hist_kernel<<<(EE + 255) / 256, 256, 0, stream>>>(dstIdx, deg, EE);
    scan1_kernel<<<nb, 256, 0, stream>>>(deg, partial, bsums, NN);
    scan2_kernel<<<1, 512, 0, stream>>>(bsums, nb);
    scan3_kernel<<<nb, 256, 0, stream>>>(partial, bsums, offs, cursor, NN);
    scatter_kernel<<<(EE + 255) / 256, 256, 0, stream>>>(srcIdx, dstIdx, cursor, srcSorted, EE);

    // ---- input projection: zbuf = relu(x @ W_in + b_in), x read as f32 ----
    inproj_kernel<<<NP / 128, 512, INPROJ_LDS, stream>>>(x, WinP, b_in, zbuf);

    // ---- GIN layers: aggregate (BN in-block) -> fused MLP (+stats slot) ----
    for (int l = 0; l < NL; ++l) {
        const float* sp = (l == 0) ? nullptr : stats + (size_t)(l - 1) * 2 * HD;
        const int gl = (l == 0) ? 0 : l - 1;
        aggregate_kernel<<<NN / 8, 256, 0, stream>>>(
            zbuf, offs, deg, srcSorted, eps, l,
            sp, gamma + (size_t)gl * HD, beta + (size_t)gl * HD, abuf);

        fused_mlp_kernel<<<NP / 128, 512, FUSED_LDS, stream>>>(
            abuf, W1P + (size_t)l * HD2 * HD, b1 + (size_t)l * HD2,
            W2P + (size_t)l * HD * HD2, b2 + (size_t)l * HD, zbuf,
            stats + (size_t)l * 2 * HD);
    }

    // ---- fused mean pool + head (BN from layer NL-1 stats slot) ----
    pool_head_kernel<<<NG, 256, 0, stream>>>(
        zbuf, batch, stats + (size_t)(NL - 1) * 2 * HD,
        gamma + (size_t)(NL - 1) * HD, beta + (size_t)(NL - 1) * HD,
        Wp1, bp1, Wp2, bp2, (float*)d_out);
}